// Round 4
// baseline (443.223 us; speedup 1.0000x reference)
//
#include <hip/hip_runtime.h>

typedef unsigned short u16;
typedef __bf16 bf8 __attribute__((ext_vector_type(8)));
typedef float f4 __attribute__((ext_vector_type(4)));

#define E_EDGES 32768
#define N_NODES 4096
// col layout of w (WNUM=6400): A[u<64][w<64] @0, B[u<64][w<16] @4096, C[u<16][w<16] @5120, D[u<16][w<64] @5376
#define N0_CONST 0.1118033988749895f       // sqrt(1/80); also equals N1*INV_SQRT3
#define INV_SQRT3_CONST 0.5773502691896258f

__device__ __forceinline__ u16 f2bf(float f) {
    unsigned u = __float_as_uint(f);
    u += 0x7FFFu + ((u >> 16) & 1u);   // RNE
    return (u16)(u >> 16);
}

// Weight prep, one launch:
//  blocks 0..399:  w2s fragment-order swizzle: w2s[mt*2048 + ks*512 + l*8 + j] =
//                  bf16(W2[(ks*32+(l>>4)*8+j)*6400 + mt*16+(l&15)])  -> af loads are 1KB contiguous/wave
//  blocks 400..415: w1t[c*128+k] = bf16(W1[k*128+c])
__global__ __launch_bounds__(256) void k_prep(const float* __restrict__ W2, const float* __restrict__ W1,
                                              u16* __restrict__ w2s, u16* __restrict__ w1t) {
    int b = blockIdx.x;
    int tid = threadIdx.x;
    if (b < 400) {
        int ks = tid >> 6, l = tid & 63;
        int el = l & 15, q4 = l >> 4;
        int c = b * 16 + el;
        u16 tmp[8];
#pragma unroll
        for (int j = 0; j < 8; j++) {
            int k = ks * 32 + q4 * 8 + j;
            tmp[j] = f2bf(W2[(size_t)k * 6400 + c]);
        }
        *(uint4*)(w2s + b * 2048 + ks * 512 + l * 8) = *(uint4*)tmp;
    } else {
        int t = (b - 400) * 256 + tid;
#pragma unroll
        for (int i = 0; i < 4; i++) {
            int idx = t * 4 + i;                // idx = c*128 + k
            int c = idx >> 7, k = idx & 127;
            w1t[idx] = f2bf(W1[k * 128 + c]);
        }
    }
}

// h = relu(edge_attr @ W1 + b1), stored bf16 [E][128]; also zeroes sums+cnt (runs before k_main)
__global__ __launch_bounds__(256) void k_h(const float* __restrict__ ea,
                                           const u16* __restrict__ w1t,
                                           const float* __restrict__ b1,
                                           u16* __restrict__ h,
                                           float* __restrict__ zbuf) {
    {   // zero sums (458752) + cnt (4096) = 462848 floats over 131072 threads
        int gid = blockIdx.x * 256 + threadIdx.x;
        for (int i = gid; i < 462848; i += 131072) zbuf[i] = 0.f;
    }
    __shared__ alignas(16) u16 ea_s[64][128];
    int tid = threadIdx.x;
    int e0 = blockIdx.x * 64;
    {
        int e = tid >> 2, q = tid & 3;
        const float4* src = (const float4*)(ea + (size_t)(e0 + e) * 128 + q * 32);
#pragma unroll
        for (int i = 0; i < 8; i++) {
            float4 f = src[i];
            int c = q * 32 + i * 4;
            ea_s[e][c + 0] = f2bf(f.x); ea_s[e][c + 1] = f2bf(f.y);
            ea_s[e][c + 2] = f2bf(f.z); ea_s[e][c + 3] = f2bf(f.w);
        }
    }
    __syncthreads();
    int lane = tid & 63, wave = tid >> 6;
    int el = lane & 15, q4 = lane >> 4;
    f4 acc[4][2];
#pragma unroll
    for (int m = 0; m < 4; m++)
#pragma unroll
        for (int nt = 0; nt < 2; nt++) acc[m][nt] = (f4){0.f, 0.f, 0.f, 0.f};
#pragma unroll
    for (int ks = 0; ks < 4; ks++) {
        bf8 a[4], b[2];
#pragma unroll
        for (int m = 0; m < 4; m++) a[m] = *(const bf8*)&ea_s[m * 16 + el][ks * 32 + q4 * 8];
#pragma unroll
        for (int nt = 0; nt < 2; nt++) {
            int n = wave * 32 + nt * 16 + el;
            b[nt] = *(const bf8*)(w1t + n * 128 + ks * 32 + q4 * 8);
        }
#pragma unroll
        for (int m = 0; m < 4; m++)
#pragma unroll
            for (int nt = 0; nt < 2; nt++)
                acc[m][nt] = __builtin_amdgcn_mfma_f32_16x16x32_bf16(a[m], b[nt], acc[m][nt], 0, 0, 0);
    }
#pragma unroll
    for (int m = 0; m < 4; m++)
#pragma unroll
        for (int nt = 0; nt < 2; nt++) {
            int n = wave * 32 + nt * 16 + el;
            float bias = b1[n];
#pragma unroll
            for (int r = 0; r < 4; r++) {
                int e = e0 + m * 16 + q4 * 4 + r;
                float v = fmaxf(acc[m][nt][r] + bias, 0.f);
                h[(size_t)e * 128 + n] = f2bf(v);
            }
        }
}

// Fused: w = h@W2+b2 (tile-by-tile) -> contraction -> scatter-atomics.
// Grid: 1024 blocks = (edge-group g, m-half). Each block: 64 edges, m-range [half*200, half*200+200).
// 4 waves; wave handles mt = half*200 + wave, step 4 (50 iters). Depth-2 register prefetch of A-fragments.
// half 0 = pure A-tiles; half 1 = A+B+C+D (B/C/D ranges all lie in [256,400)).
__global__ __launch_bounds__(256, 3) void k_main(const u16* __restrict__ w2s,
                                                 const u16* __restrict__ hgl,
                                                 const float* __restrict__ b2,
                                                 const float* __restrict__ node_attr,
                                                 const int* __restrict__ edge_index,
                                                 const float* __restrict__ edge_sh,
                                                 float* __restrict__ sums,
                                                 float* __restrict__ cnt) {
    __shared__ union {
        u16 h[64][128];                                    // 16384 B (prologue only)
        struct { float accC[48][66]; float redB[16][66]; } a;  // 16896 B (M-loop + epilogue)
    } ovl;
    __shared__ float sT[64][64];               // 16 KB  s[u][e]
    __shared__ float vT[3][16][64];            // 12 KB  v[i][u][e]
    __shared__ float pT[16][64];               // 4 KB   INV_SQRT3*(v.sh1)[u][e]
    __shared__ float sh0_s[64];
    __shared__ float sh1_s[3][64];
    __shared__ int src_s[64];
    __shared__ int dst_s[64];

    int tid = threadIdx.x;
    int g = blockIdx.x >> 1;
    int half = blockIdx.x & 1;
    int e0 = g * 64;

    // phase 1: edge meta
    if (tid < 64) {
        int ge = e0 + tid;
        src_s[tid] = edge_index[ge];
        dst_s[tid] = edge_index[E_EDGES + ge];
        float4 sh = *(const float4*)(edge_sh + (size_t)ge * 4);
        sh0_s[tid] = sh.x; sh1_s[0][tid] = sh.y; sh1_s[1][tid] = sh.z; sh1_s[2][tid] = sh.w;
    }
    __syncthreads();

    // phase 2: node features (transposed into LDS) + h tile into ovl.h
    {
        int e = tid >> 2, q = tid & 3;
        int dst = dst_s[e];
        const float* xp = node_attr + (size_t)dst * 112;
#pragma unroll
        for (int i = 0; i < 4; i++) {
            float4 f = *(const float4*)(xp + q * 16 + i * 4);
            int u = q * 16 + i * 4;
            sT[u + 0][e] = f.x; sT[u + 1][e] = f.y; sT[u + 2][e] = f.z; sT[u + 3][e] = f.w;
        }
        float vv[12];
#pragma unroll
        for (int i = 0; i < 3; i++) {
            float4 f = *(const float4*)(xp + 64 + q * 12 + i * 4);
            vv[i * 4 + 0] = f.x; vv[i * 4 + 1] = f.y; vv[i * 4 + 2] = f.z; vv[i * 4 + 3] = f.w;
        }
        float s1x = sh1_s[0][e], s1y = sh1_s[1][e], s1z = sh1_s[2][e];
#pragma unroll
        for (int u = 0; u < 4; u++) {
            float xa = vv[u * 3 + 0], xb = vv[u * 3 + 1], xc = vv[u * 3 + 2];
            int uu = q * 4 + u;
            vT[0][uu][e] = xa; vT[1][uu][e] = xb; vT[2][uu][e] = xc;
            pT[uu][e] = INV_SQRT3_CONST * (xa * s1x + xb * s1y + xc * s1z);
        }
        const uint4* hsrc = (const uint4*)(hgl + (size_t)(e0 + e) * 128) + q * 4;
        uint4* hdst = (uint4*)(&ovl.h[e][q * 32]);
#pragma unroll
        for (int i = 0; i < 4; i++) hdst[i] = hsrc[i];
    }
    __syncthreads();

    int lane = tid & 63, wave = tid >> 6;
    int el = lane & 15, q4 = lane >> 4;

    // B-fragments (h) resident for whole block
    bf8 hb[4][4];
#pragma unroll
    for (int n = 0; n < 4; n++)
#pragma unroll
        for (int ks = 0; ks < 4; ks++)
            hb[n][ks] = *(const bf8*)&ovl.h[n * 16 + el][ks * 32 + q4 * 8];
    float sh0n[4];
#pragma unroll
    for (int n = 0; n < 4; n++) sh0n[n] = sh0_s[n * 16 + el];
    __syncthreads();   // everyone done reading ovl.h; overlay becomes accC/redB

    // zero accC + redB (contiguous, 4224 floats)
    for (int i = tid; i < 4224; i += 256) ((float*)&ovl.a)[i] = 0.f;
    __syncthreads();

    f4 acc0[4], accB[4];
#pragma unroll
    for (int n = 0; n < 4; n++) { acc0[n] = (f4){0.f,0.f,0.f,0.f}; accB[n] = (f4){0.f,0.f,0.f,0.f}; }

    const int mt0 = half * 200 + wave;
    const int mtEnd = half * 200 + 200;
    const u16* abase = w2s + lane * 8;  // + mt*2048 + ks*512 : fully coalesced 1KB/wave-load

    // depth-2 register prefetch
    bf8 af0[4], af1[4]; float4 b20, b21;
    {
        const u16* p0 = abase + (size_t)mt0 * 2048;
        const u16* p1 = abase + (size_t)(mt0 + 4) * 2048;
#pragma unroll
        for (int ks = 0; ks < 4; ks++) { af0[ks] = *(const bf8*)(p0 + ks * 512); af1[ks] = *(const bf8*)(p1 + ks * 512); }
        b20 = *(const float4*)(b2 + mt0 * 16 + q4 * 4);
        b21 = *(const float4*)(b2 + (mt0 + 4) * 16 + q4 * 4);
    }

    for (int mt = mt0; mt < mtEnd; mt += 4) {
        int mt2 = (mt + 8 < mtEnd) ? (mt + 8) : mt;
        bf8 af2[4]; float4 b22;
        {
            const u16* p = abase + (size_t)mt2 * 2048;
#pragma unroll
            for (int ks = 0; ks < 4; ks++) af2[ks] = *(const bf8*)(p + ks * 512);
            b22 = *(const float4*)(b2 + mt2 * 16 + q4 * 4);
        }
        f4 wf[4];
#pragma unroll
        for (int n = 0; n < 4; n++) wf[n] = (f4){b20.x, b20.y, b20.z, b20.w};
#pragma unroll
        for (int ks = 0; ks < 4; ks++)
#pragma unroll
            for (int n = 0; n < 4; n++)
                wf[n] = __builtin_amdgcn_mfma_f32_16x16x32_bf16(af0[ks], hb[n][ks], wf[n], 0, 0, 0);

        int c0 = mt * 16;
        if (c0 < 4096) {                    // A: scale sh0*s[u], out0 rows wave*16..+16
            int u = c0 >> 6;
#pragma unroll
            for (int n = 0; n < 4; n++) {
                float sv = sh0n[n] * sT[u][n * 16 + el];
                acc0[n] += sv * wf[n];
            }
        } else if (c0 < 5120) {             // B: scale s[u] (cross-wave partial)
            int u = (c0 - 4096) >> 4;
#pragma unroll
            for (int n = 0; n < 4; n++) {
                float sv = sT[u][n * 16 + el];
                accB[n] += sv * wf[n];
            }
        } else if (c0 < 5376) {             // C: scales v[i][u], into LDS (cross-wave partial)
            int u = (c0 - 5120) >> 4;
#pragma unroll
            for (int n = 0; n < 4; n++) {
                int e = n * 16 + el;
#pragma unroll
                for (int i = 0; i < 3; i++) {
                    float sv = vT[i][u][e];
#pragma unroll
                    for (int r = 0; r < 4; r++)
                        unsafeAtomicAdd(&ovl.a.accC[i * 16 + q4 * 4 + r][e], sv * wf[n][r]);
                }
            }
        } else {                            // D: scale p[u], out0 rows wave*16..+16
            int u = (c0 - 5376) >> 6;
#pragma unroll
            for (int n = 0; n < 4; n++) {
                float sv = pT[u][n * 16 + el];
                acc0[n] += sv * wf[n];
            }
        }
#pragma unroll
        for (int ks = 0; ks < 4; ks++) { af0[ks] = af1[ks]; af1[ks] = af2[ks]; }
        b20 = b21; b21 = b22;
    }

    // out0 scatter: each wave owns complete rows [wave*16, wave*16+16) of its half's contributions
#pragma unroll
    for (int n = 0; n < 4; n++) {
        int e = n * 16 + el;
        int base = src_s[e] * 112 + wave * 16 + q4 * 4;
#pragma unroll
        for (int r = 0; r < 4; r++)
            unsafeAtomicAdd(&sums[base + r], N0_CONST * acc0[n][r]);
    }
    if (half == 1) {
        // accB partials -> redB (disjoint LDS region; safe concurrent with other waves' accC atomics)
#pragma unroll
        for (int n = 0; n < 4; n++) {
            int e = n * 16 + el;
#pragma unroll
            for (int r = 0; r < 4; r++)
                unsafeAtomicAdd(&ovl.a.redB[q4 * 4 + r][e], accB[n][r]);
        }
        __syncthreads();   // all waves' M-loop (accC) + redB atomics complete
        // out1 scatter: col 64 + w'*3 + i = N0*(B_pre[w']*sh1[i] + C_pre[i][w']*sh0)
        for (int idx = tid; idx < 64 * 48; idx += 256) {
            int e = idx / 48;
            int cr = idx - e * 48;
            int wp = cr / 3;
            int i = cr - wp * 3;
            float val = N0_CONST * (ovl.a.redB[wp][e] * sh1_s[i][e] + ovl.a.accC[i * 16 + wp][e] * sh0_s[e]);
            unsafeAtomicAdd(&sums[src_s[e] * 112 + 64 + cr], val);
        }
    } else {
        if (tid < 64) unsafeAtomicAdd(&cnt[src_s[tid]], 1.0f);
    }
}

__global__ void k_final(const float* __restrict__ sums, const float* __restrict__ cnt,
                        const float* __restrict__ node_attr, float* __restrict__ out) {
    int idx = blockIdx.x * 256 + threadIdx.x;
    if (idx < N_NODES * 112) {
        int n = idx / 112;
        float c = fmaxf(cnt[n], 1.f);
        out[idx] = sums[idx] / c + node_attr[idx];
    }
}

extern "C" void kernel_launch(void* const* d_in, const int* in_sizes, int n_in,
                              void* d_out, int out_size, void* d_ws, size_t ws_size,
                              hipStream_t stream) {
    const float* node_attr  = (const float*)d_in[0];
    const int*   edge_index = (const int*)d_in[1];
    const float* edge_attr  = (const float*)d_in[2];
    const float* edge_sh    = (const float*)d_in[3];
    const float* W1         = (const float*)d_in[6];
    const float* b1         = (const float*)d_in[7];
    const float* W2         = (const float*)d_in[8];
    const float* b2         = (const float*)d_in[9];
    float* out = (float*)d_out;

    char* ws = (char*)d_ws;
    u16*   w2s  = (u16*)ws;                       // 6400*128*2 = 1,638,400
    u16*   w1t  = (u16*)(ws + 1638400);           // 128*128*2  =    32,768
    u16*   hgl  = (u16*)(ws + 1671168);           // 32768*128*2 = 8,388,608
    float* sums = (float*)(ws + 10059776);        // 4096*112*4 = 1,835,008
    float* cnt  = (float*)(ws + 11894784);        // 4096*4     =    16,384  (contiguous after sums)

    k_prep<<<416, 256, 0, stream>>>(W2, W1, w2s, w1t);
    k_h<<<512, 256, 0, stream>>>(edge_attr, w1t, b1, hgl, sums);
    k_main<<<1024, 256, 0, stream>>>(w2s, hgl, b2, node_attr, edge_index, edge_sh, sums, cnt);
    k_final<<<1792, 256, 0, stream>>>(sums, cnt, node_attr, out);
}

// Round 5
// 353.702 us; speedup vs baseline: 1.2531x; 1.2531x over previous
//
#include <hip/hip_runtime.h>

typedef unsigned short u16;
typedef __bf16 bf8 __attribute__((ext_vector_type(8)));
typedef float f4 __attribute__((ext_vector_type(4)));

#define E_EDGES 32768
#define N_NODES 4096
// col layout of w (WNUM=6400): A[u<64][w<64] @0, B[u<64][w<16] @4096, C[u<16][w<16] @5120, D[u<16][w<64] @5376
#define N0_CONST 0.1118033988749895f       // sqrt(1/80); also equals N1*INV_SQRT3
#define INV_SQRT3_CONST 0.5773502691896258f

__device__ __forceinline__ u16 f2bf(float f) {
    unsigned u = __float_as_uint(f);
    u += 0x7FFFu + ((u >> 16) & 1u);   // RNE
    return (u16)(u >> 16);
}

// Weight prep + src-degree histogram, one launch:
//  blocks 0..399:   w2s fragment-order swizzle (af loads 1KB contiguous/wave)
//  blocks 400..415: w1t[c*128+k] = bf16(W1[k*128+c])
//  blocks 416..543: deg histogram over edge src (deg pre-zeroed by memsetAsync)
__global__ __launch_bounds__(256) void k_prep(const float* __restrict__ W2, const float* __restrict__ W1,
                                              const int* __restrict__ edge_index,
                                              u16* __restrict__ w2s, u16* __restrict__ w1t,
                                              int* __restrict__ deg) {
    int b = blockIdx.x;
    int tid = threadIdx.x;
    if (b < 400) {
        int ks = tid >> 6, l = tid & 63;
        int el = l & 15, q4 = l >> 4;
        int c = b * 16 + el;
        u16 tmp[8];
#pragma unroll
        for (int j = 0; j < 8; j++) {
            int k = ks * 32 + q4 * 8 + j;
            tmp[j] = f2bf(W2[(size_t)k * 6400 + c]);
        }
        *(uint4*)(w2s + b * 2048 + ks * 512 + l * 8) = *(uint4*)tmp;
    } else if (b < 416) {
        int t = (b - 400) * 256 + tid;
#pragma unroll
        for (int i = 0; i < 4; i++) {
            int idx = t * 4 + i;                // idx = c*128 + k
            int c = idx >> 7, k = idx & 127;
            w1t[idx] = f2bf(W1[k * 128 + c]);
        }
    } else {
        int t = (b - 416) * 256 + tid;          // 128 blocks * 256 = 32768 = E
        atomicAdd(&deg[edge_index[t]], 1);
    }
}

// Exclusive scan of deg[4096] -> ptr[0..4096] and cursor copy. 1 block, 64 threads.
__global__ void k_scan(const int* __restrict__ deg, int* __restrict__ ptr, int* __restrict__ cursor) {
    int t = threadIdx.x;           // 0..63
    int base = t * 64;
    int s = 0;
    for (int i = 0; i < 64; i++) s += deg[base + i];
    int x = s;
#pragma unroll
    for (int d = 1; d < 64; d <<= 1) {
        int y = __shfl_up(x, d, 64);
        if (t >= d) x += y;
    }
    int run = x - s;               // exclusive prefix
    for (int i = 0; i < 64; i++) {
        ptr[base + i] = run;
        cursor[base + i] = run;
        run += deg[base + i];
    }
    if (t == 63) ptr[4096] = run;
}

// h = relu(edge_attr @ W1 + b1), stored bf16 [E][128]; also fills CSR edge-id list via cursor
__global__ __launch_bounds__(256) void k_h(const float* __restrict__ ea,
                                           const u16* __restrict__ w1t,
                                           const float* __restrict__ b1,
                                           const int* __restrict__ edge_index,
                                           int* __restrict__ cursor,
                                           int* __restrict__ eids,
                                           u16* __restrict__ h) {
    __shared__ alignas(16) u16 ea_s[64][128];
    int tid = threadIdx.x;
    int e0 = blockIdx.x * 64;
    if (tid < 64) {                // CSR fill for this block's 64 edges
        int ge = e0 + tid;
        int s = edge_index[ge];
        int pos = atomicAdd(&cursor[s], 1);
        eids[pos] = ge;
    }
    {
        int e = tid >> 2, q = tid & 3;
        const float4* src = (const float4*)(ea + (size_t)(e0 + e) * 128 + q * 32);
#pragma unroll
        for (int i = 0; i < 8; i++) {
            float4 f = src[i];
            int c = q * 32 + i * 4;
            ea_s[e][c + 0] = f2bf(f.x); ea_s[e][c + 1] = f2bf(f.y);
            ea_s[e][c + 2] = f2bf(f.z); ea_s[e][c + 3] = f2bf(f.w);
        }
    }
    __syncthreads();
    int lane = tid & 63, wave = tid >> 6;
    int el = lane & 15, q4 = lane >> 4;
    f4 acc[4][2];
#pragma unroll
    for (int m = 0; m < 4; m++)
#pragma unroll
        for (int nt = 0; nt < 2; nt++) acc[m][nt] = (f4){0.f, 0.f, 0.f, 0.f};
#pragma unroll
    for (int ks = 0; ks < 4; ks++) {
        bf8 a[4], b[2];
#pragma unroll
        for (int m = 0; m < 4; m++) a[m] = *(const bf8*)&ea_s[m * 16 + el][ks * 32 + q4 * 8];
#pragma unroll
        for (int nt = 0; nt < 2; nt++) {
            int n = wave * 32 + nt * 16 + el;
            b[nt] = *(const bf8*)(w1t + n * 128 + ks * 32 + q4 * 8);
        }
#pragma unroll
        for (int m = 0; m < 4; m++)
#pragma unroll
            for (int nt = 0; nt < 2; nt++)
                acc[m][nt] = __builtin_amdgcn_mfma_f32_16x16x32_bf16(a[m], b[nt], acc[m][nt], 0, 0, 0);
    }
#pragma unroll
    for (int m = 0; m < 4; m++)
#pragma unroll
        for (int nt = 0; nt < 2; nt++) {
            int n = wave * 32 + nt * 16 + el;
            float bias = b1[n];
#pragma unroll
            for (int r = 0; r < 4; r++) {
                int e = e0 + m * 16 + q4 * 4 + r;
                float v = fmaxf(acc[m][nt][r] + bias, 0.f);
                h[(size_t)e * 128 + n] = f2bf(v);
            }
        }
}

// Fused: w = h@W2+b2 (tile-by-tile) -> contraction -> dense per-edge tp[E][112] (NO atomics).
// 256 threads = 4 waves; wave = m-group (stride 4, 100 iters); depth-2 register prefetch of A.
__global__ __launch_bounds__(256, 3) void k_main(const u16* __restrict__ w2s,
                                                 const u16* __restrict__ hgl,
                                                 const float* __restrict__ b2,
                                                 const float* __restrict__ node_attr,
                                                 const int* __restrict__ edge_index,
                                                 const float* __restrict__ edge_sh,
                                                 float* __restrict__ tp) {
    __shared__ union {
        u16 h[64][128];                                    // 16384 B (prologue only)
        struct { float accC[48][66]; float redB[16][66]; } a;  // 16896 B (M-loop + epilogue)
    } ovl;
    __shared__ float sT[64][65];               // s[u][e] (padded: conflict-free); reused as out0[e][c] in epilogue
    __shared__ float vT[3][16][66];            // v[i][u][e] (padded)
    __shared__ float pT[16][66];               // INV_SQRT3*(v.sh1)[u][e] (padded)
    __shared__ float sh0_s[64];
    __shared__ float sh1_s[3][64];
    __shared__ int dst_s[64];

    int tid = threadIdx.x;
    int e0 = blockIdx.x * 64;

    // phase 1: edge meta
    if (tid < 64) {
        int ge = e0 + tid;
        dst_s[tid] = edge_index[E_EDGES + ge];
        float4 sh = *(const float4*)(edge_sh + (size_t)ge * 4);
        sh0_s[tid] = sh.x; sh1_s[0][tid] = sh.y; sh1_s[1][tid] = sh.z; sh1_s[2][tid] = sh.w;
    }
    __syncthreads();

    // phase 2: node features (transposed into LDS) + h tile into ovl.h
    {
        int e = tid >> 2, q = tid & 3;
        int dst = dst_s[e];
        const float* xp = node_attr + (size_t)dst * 112;
#pragma unroll
        for (int i = 0; i < 4; i++) {
            float4 f = *(const float4*)(xp + q * 16 + i * 4);
            int u = q * 16 + i * 4;
            sT[u + 0][e] = f.x; sT[u + 1][e] = f.y; sT[u + 2][e] = f.z; sT[u + 3][e] = f.w;
        }
        float vv[12];
#pragma unroll
        for (int i = 0; i < 3; i++) {
            float4 f = *(const float4*)(xp + 64 + q * 12 + i * 4);
            vv[i * 4 + 0] = f.x; vv[i * 4 + 1] = f.y; vv[i * 4 + 2] = f.z; vv[i * 4 + 3] = f.w;
        }
        float s1x = sh1_s[0][e], s1y = sh1_s[1][e], s1z = sh1_s[2][e];
#pragma unroll
        for (int u = 0; u < 4; u++) {
            float xa = vv[u * 3 + 0], xb = vv[u * 3 + 1], xc = vv[u * 3 + 2];
            int uu = q * 4 + u;
            vT[0][uu][e] = xa; vT[1][uu][e] = xb; vT[2][uu][e] = xc;
            pT[uu][e] = INV_SQRT3_CONST * (xa * s1x + xb * s1y + xc * s1z);
        }
        const uint4* hsrc = (const uint4*)(hgl + (size_t)(e0 + e) * 128) + q * 4;
        uint4* hdst = (uint4*)(&ovl.h[e][q * 32]);
#pragma unroll
        for (int i = 0; i < 4; i++) hdst[i] = hsrc[i];
    }
    __syncthreads();

    int lane = tid & 63, wave = tid >> 6;
    int el = lane & 15, q4 = lane >> 4;

    // B-fragments (h) resident for whole block
    bf8 hb[4][4];
#pragma unroll
    for (int n = 0; n < 4; n++)
#pragma unroll
        for (int ks = 0; ks < 4; ks++)
            hb[n][ks] = *(const bf8*)&ovl.h[n * 16 + el][ks * 32 + q4 * 8];
    float sh0n[4];
#pragma unroll
    for (int n = 0; n < 4; n++) sh0n[n] = sh0_s[n * 16 + el];
    __syncthreads();   // everyone done reading ovl.h; overlay becomes accC/redB

    // zero accC + redB (contiguous, 4224 floats)
    for (int i = tid; i < 4224; i += 256) ((float*)&ovl.a)[i] = 0.f;
    __syncthreads();

    f4 acc0[4], accB[4];
#pragma unroll
    for (int n = 0; n < 4; n++) { acc0[n] = (f4){0.f,0.f,0.f,0.f}; accB[n] = (f4){0.f,0.f,0.f,0.f}; }

    const u16* abase = w2s + lane * 8;  // + mt*2048 + ks*512 : fully coalesced 1KB/wave-load

    // depth-2 register prefetch
    bf8 af0[4], af1[4]; float4 b20, b21;
    {
        const u16* p0 = abase + (size_t)wave * 2048;
        const u16* p1 = abase + (size_t)(wave + 4) * 2048;
#pragma unroll
        for (int ks = 0; ks < 4; ks++) { af0[ks] = *(const bf8*)(p0 + ks * 512); af1[ks] = *(const bf8*)(p1 + ks * 512); }
        b20 = *(const float4*)(b2 + wave * 16 + q4 * 4);
        b21 = *(const float4*)(b2 + (wave + 4) * 16 + q4 * 4);
    }

    for (int mt = wave; mt < 400; mt += 4) {
        int mt2 = (mt + 8 < 400) ? (mt + 8) : mt;
        bf8 af2[4]; float4 b22;
        {
            const u16* p = abase + (size_t)mt2 * 2048;
#pragma unroll
            for (int ks = 0; ks < 4; ks++) af2[ks] = *(const bf8*)(p + ks * 512);
            b22 = *(const float4*)(b2 + mt2 * 16 + q4 * 4);
        }
        f4 wf[4];
#pragma unroll
        for (int n = 0; n < 4; n++) wf[n] = (f4){b20.x, b20.y, b20.z, b20.w};
#pragma unroll
        for (int ks = 0; ks < 4; ks++)
#pragma unroll
            for (int n = 0; n < 4; n++)
                wf[n] = __builtin_amdgcn_mfma_f32_16x16x32_bf16(af0[ks], hb[n][ks], wf[n], 0, 0, 0);

        int c0 = mt * 16;
        if (c0 < 4096) {                    // A: scale sh0*s[u], out0 rows wave*16..+16
            int u = c0 >> 6;
#pragma unroll
            for (int n = 0; n < 4; n++) {
                float sv = sh0n[n] * sT[u][n * 16 + el];
                acc0[n] += sv * wf[n];
            }
        } else if (c0 < 5120) {             // B: scale s[u] (cross-wave partial)
            int u = (c0 - 4096) >> 4;
#pragma unroll
            for (int n = 0; n < 4; n++) {
                float sv = sT[u][n * 16 + el];
                accB[n] += sv * wf[n];
            }
        } else if (c0 < 5376) {             // C: scales v[i][u], into LDS (cross-wave partial)
            int u = (c0 - 5120) >> 4;
#pragma unroll
            for (int n = 0; n < 4; n++) {
                int e = n * 16 + el;
#pragma unroll
                for (int i = 0; i < 3; i++) {
                    float sv = vT[i][u][e];
#pragma unroll
                    for (int r = 0; r < 4; r++)
                        unsafeAtomicAdd(&ovl.a.accC[i * 16 + q4 * 4 + r][e], sv * wf[n][r]);
                }
            }
        } else {                            // D: scale p[u], out0 rows wave*16..+16
            int u = (c0 - 5376) >> 6;
#pragma unroll
            for (int n = 0; n < 4; n++) {
                float sv = pT[u][n * 16 + el];
                acc0[n] += sv * wf[n];
            }
        }
#pragma unroll
        for (int ks = 0; ks < 4; ks++) { af0[ks] = af1[ks]; af1[ks] = af2[ks]; }
        b20 = b21; b21 = b22;
    }

    // accB partials -> redB (disjoint LDS region; safe concurrent with other waves' accC atomics)
#pragma unroll
    for (int n = 0; n < 4; n++) {
        int e = n * 16 + el;
#pragma unroll
        for (int r = 0; r < 4; r++)
            unsafeAtomicAdd(&ovl.a.redB[q4 * 4 + r][e], accB[n][r]);
    }
    __syncthreads();   // all waves done with M-loop (sT reads) + accC/redB atomics

    // stage out0 into sT (now dead): sT[e][c], wave owns cols [wave*16, wave*16+16)
#pragma unroll
    for (int n = 0; n < 4; n++) {
        int e = n * 16 + el;
#pragma unroll
        for (int r = 0; r < 4; r++)
            sT[e][wave * 16 + q4 * 4 + r] = N0_CONST * acc0[n][r];
    }
    __syncthreads();

    // single fully-coalesced 28KB store of tp[e0..e0+64)[0..112)
    float* tpe = tp + (size_t)e0 * 112;
    for (int idx = tid; idx < 64 * 112; idx += 256) {
        int e = idx / 112;
        int c = idx - e * 112;
        float val;
        if (c < 64) {
            val = sT[e][c];
        } else {
            int cr = c - 64;
            int wp = cr / 3;
            int i = cr - wp * 3;
            val = N0_CONST * (ovl.a.redB[wp][e] * sh1_s[i][e] + ovl.a.accC[i * 16 + wp][e] * sh0_s[e]);
        }
        tpe[idx] = val;
    }
}

// Per-node segment mean over CSR edge list + residual. Block = node, thread = col.
__global__ __launch_bounds__(128) void k_red(const float* __restrict__ tp,
                                             const int* __restrict__ ptr,
                                             const int* __restrict__ eids,
                                             const float* __restrict__ node_attr,
                                             float* __restrict__ out) {
    int n = blockIdx.x;
    int c = threadIdx.x;
    if (c >= 112) return;
    int a = ptr[n], b = ptr[n + 1];
    float s = 0.f;
    for (int i = a; i < b; i++) {
        int e = eids[i];
        s += tp[(size_t)e * 112 + c];
    }
    float d = fmaxf((float)(b - a), 1.f);
    out[n * 112 + c] = s / d + node_attr[n * 112 + c];
}

extern "C" void kernel_launch(void* const* d_in, const int* in_sizes, int n_in,
                              void* d_out, int out_size, void* d_ws, size_t ws_size,
                              hipStream_t stream) {
    const float* node_attr  = (const float*)d_in[0];
    const int*   edge_index = (const int*)d_in[1];
    const float* edge_attr  = (const float*)d_in[2];
    const float* edge_sh    = (const float*)d_in[3];
    const float* W1         = (const float*)d_in[6];
    const float* b1         = (const float*)d_in[7];
    const float* W2         = (const float*)d_in[8];
    const float* b2         = (const float*)d_in[9];
    float* out = (float*)d_out;

    char* ws = (char*)d_ws;
    u16*   w2s    = (u16*)ws;                     // 6400*128*2  = 1,638,400
    u16*   w1t    = (u16*)(ws + 1638400);         // 128*128*2   =    32,768
    u16*   hgl    = (u16*)(ws + 1671168);         // 32768*128*2 = 8,388,608
    float* tp     = (float*)(ws + 10059776);      // 32768*112*4 = 14,680,064
    int*   deg    = (int*)(ws + 24739840);        // 4096*4      =    16,384
    int*   ptr    = (int*)(ws + 24756224);        // 4097*4 (pad to 16,400)
    int*   cursor = (int*)(ws + 24772624);        // 4096*4      =    16,384
    int*   eids   = (int*)(ws + 24789024);        // 32768*4     =   131,072  -> total ~24.9 MB

    hipMemsetAsync(deg, 0, 16384, stream);
    k_prep<<<544, 256, 0, stream>>>(W2, W1, edge_index, w2s, w1t, deg);
    k_scan<<<1, 64, 0, stream>>>(deg, ptr, cursor);
    k_h<<<512, 256, 0, stream>>>(edge_attr, w1t, b1, edge_index, cursor, eids, hgl);
    k_main<<<512, 256, 0, stream>>>(w2s, hgl, b2, node_attr, edge_index, edge_sh, tp);
    k_red<<<4096, 128, 0, stream>>>(tp, ptr, eids, node_attr, out);
}

// Round 6
// 301.185 us; speedup vs baseline: 1.4716x; 1.1744x over previous
//
#include <hip/hip_runtime.h>

typedef unsigned short u16;
typedef __bf16 bf8 __attribute__((ext_vector_type(8)));
typedef float f4 __attribute__((ext_vector_type(4)));

#define E_EDGES 32768
#define N_NODES 4096
// col layout of w (WNUM=6400): A[u<64][w<64] @0, B[u<64][w<16] @4096, C[u<16][w<16] @5120, D[u<16][w<64] @5376
#define N0_CONST 0.1118033988749895f       // sqrt(1/80); also equals N1*INV_SQRT3
#define INV_SQRT3_CONST 0.5773502691896258f

__device__ __forceinline__ u16 f2bf(float f) {
    unsigned u = __float_as_uint(f);
    u += 0x7FFFu + ((u >> 16) & 1u);   // RNE
    return (u16)(u >> 16);
}

// Weight prep + src-degree histogram, one launch:
//  blocks 0..399:   w2s fragment-order swizzle (af loads 1KB contiguous/wave)
//  blocks 400..415: w1t[c*128+k] = bf16(W1[k*128+c])
//  blocks 416..543: deg histogram over edge src (deg pre-zeroed by memsetAsync)
__global__ __launch_bounds__(256) void k_prep(const float* __restrict__ W2, const float* __restrict__ W1,
                                              const int* __restrict__ edge_index,
                                              u16* __restrict__ w2s, u16* __restrict__ w1t,
                                              int* __restrict__ deg) {
    int b = blockIdx.x;
    int tid = threadIdx.x;
    if (b < 400) {
        int ks = tid >> 6, l = tid & 63;
        int el = l & 15, q4 = l >> 4;
        int c = b * 16 + el;
        u16 tmp[8];
#pragma unroll
        for (int j = 0; j < 8; j++) {
            int k = ks * 32 + q4 * 8 + j;
            tmp[j] = f2bf(W2[(size_t)k * 6400 + c]);
        }
        *(uint4*)(w2s + b * 2048 + ks * 512 + l * 8) = *(uint4*)tmp;
    } else if (b < 416) {
        int t = (b - 400) * 256 + tid;
#pragma unroll
        for (int i = 0; i < 4; i++) {
            int idx = t * 4 + i;                // idx = c*128 + k
            int c = idx >> 7, k = idx & 127;
            w1t[idx] = f2bf(W1[k * 128 + c]);
        }
    } else {
        int t = (b - 416) * 256 + tid;          // 128 blocks * 256 = 32768 = E
        atomicAdd(&deg[edge_index[t]], 1);
    }
}

// Exclusive scan of deg[4096] -> ptr[0..4096] and cursor copy. 1 block, 64 threads.
__global__ void k_scan(const int* __restrict__ deg, int* __restrict__ ptr, int* __restrict__ cursor) {
    int t = threadIdx.x;           // 0..63
    int base = t * 64;
    int s = 0;
    for (int i = 0; i < 64; i++) s += deg[base + i];
    int x = s;
#pragma unroll
    for (int d = 1; d < 64; d <<= 1) {
        int y = __shfl_up(x, d, 64);
        if (t >= d) x += y;
    }
    int run = x - s;               // exclusive prefix
    for (int i = 0; i < 64; i++) {
        ptr[base + i] = run;
        cursor[base + i] = run;
        run += deg[base + i];
    }
    if (t == 63) ptr[4096] = run;
}

// h = relu(edge_attr @ W1 + b1), stored bf16 [E][128]; also fills CSR edge-id list via cursor
__global__ __launch_bounds__(256) void k_h(const float* __restrict__ ea,
                                           const u16* __restrict__ w1t,
                                           const float* __restrict__ b1,
                                           const int* __restrict__ edge_index,
                                           int* __restrict__ cursor,
                                           int* __restrict__ eids,
                                           u16* __restrict__ h) {
    __shared__ alignas(16) u16 ea_s[64][128];
    int tid = threadIdx.x;
    int e0 = blockIdx.x * 64;
    if (tid < 64) {                // CSR fill for this block's 64 edges
        int ge = e0 + tid;
        int s = edge_index[ge];
        int pos = atomicAdd(&cursor[s], 1);
        eids[pos] = ge;
    }
    {
        int e = tid >> 2, q = tid & 3;
        const float4* src = (const float4*)(ea + (size_t)(e0 + e) * 128 + q * 32);
#pragma unroll
        for (int i = 0; i < 8; i++) {
            float4 f = src[i];
            int c = q * 32 + i * 4;
            ea_s[e][c + 0] = f2bf(f.x); ea_s[e][c + 1] = f2bf(f.y);
            ea_s[e][c + 2] = f2bf(f.z); ea_s[e][c + 3] = f2bf(f.w);
        }
    }
    __syncthreads();
    int lane = tid & 63, wave = tid >> 6;
    int el = lane & 15, q4 = lane >> 4;
    f4 acc[4][2];
#pragma unroll
    for (int m = 0; m < 4; m++)
#pragma unroll
        for (int nt = 0; nt < 2; nt++) acc[m][nt] = (f4){0.f, 0.f, 0.f, 0.f};
#pragma unroll
    for (int ks = 0; ks < 4; ks++) {
        bf8 a[4], b[2];
#pragma unroll
        for (int m = 0; m < 4; m++) a[m] = *(const bf8*)&ea_s[m * 16 + el][ks * 32 + q4 * 8];
#pragma unroll
        for (int nt = 0; nt < 2; nt++) {
            int n = wave * 32 + nt * 16 + el;
            b[nt] = *(const bf8*)(w1t + n * 128 + ks * 32 + q4 * 8);
        }
#pragma unroll
        for (int m = 0; m < 4; m++)
#pragma unroll
            for (int nt = 0; nt < 2; nt++)
                acc[m][nt] = __builtin_amdgcn_mfma_f32_16x16x32_bf16(a[m], b[nt], acc[m][nt], 0, 0, 0);
    }
#pragma unroll
    for (int m = 0; m < 4; m++)
#pragma unroll
        for (int nt = 0; nt < 2; nt++) {
            int n = wave * 32 + nt * 16 + el;
            float bias = b1[n];
#pragma unroll
            for (int r = 0; r < 4; r++) {
                int e = e0 + m * 16 + q4 * 4 + r;
                float v = fmaxf(acc[m][nt][r] + bias, 0.f);
                h[(size_t)e * 128 + n] = f2bf(v);
            }
        }
}

// Fused: w = h@W2+b2 (tile-by-tile) -> contraction -> dense per-edge tp[E][112] (NO atomics).
// 256 threads = 4 waves; wave = m-group (stride 4, 100 iters, manually unrolled x2).
// Two named prefetch buffers, NO rotation copies -> no vmcnt(0) drain per iteration.
__global__ __launch_bounds__(256, 2) void k_main(const u16* __restrict__ w2s,
                                                 const u16* __restrict__ hgl,
                                                 const float* __restrict__ b2,
                                                 const float* __restrict__ node_attr,
                                                 const int* __restrict__ edge_index,
                                                 const float* __restrict__ edge_sh,
                                                 float* __restrict__ tp) {
    __shared__ union {
        u16 h[64][128];                                    // 16384 B (prologue only)
        struct { float accC[48][66]; float redB[16][66]; } a;  // 16896 B (M-loop + epilogue)
    } ovl;
    __shared__ float sT[64][65];               // s[u][e] (padded); reused as out0[e][c] in epilogue
    __shared__ float vT[3][16][66];            // v[i][u][e] (padded)
    __shared__ float pT[16][66];               // INV_SQRT3*(v.sh1)[u][e] (padded)
    __shared__ float sh0_s[64];
    __shared__ float sh1_s[3][64];
    __shared__ int dst_s[64];

    int tid = threadIdx.x;
    int e0 = blockIdx.x * 64;

    // phase 1: edge meta
    if (tid < 64) {
        int ge = e0 + tid;
        dst_s[tid] = edge_index[E_EDGES + ge];
        float4 sh = *(const float4*)(edge_sh + (size_t)ge * 4);
        sh0_s[tid] = sh.x; sh1_s[0][tid] = sh.y; sh1_s[1][tid] = sh.z; sh1_s[2][tid] = sh.w;
    }
    __syncthreads();

    // phase 2: node features (transposed into LDS) + h tile into ovl.h
    {
        int e = tid >> 2, q = tid & 3;
        int dst = dst_s[e];
        const float* xp = node_attr + (size_t)dst * 112;
#pragma unroll
        for (int i = 0; i < 4; i++) {
            float4 f = *(const float4*)(xp + q * 16 + i * 4);
            int u = q * 16 + i * 4;
            sT[u + 0][e] = f.x; sT[u + 1][e] = f.y; sT[u + 2][e] = f.z; sT[u + 3][e] = f.w;
        }
        float vv[12];
#pragma unroll
        for (int i = 0; i < 3; i++) {
            float4 f = *(const float4*)(xp + 64 + q * 12 + i * 4);
            vv[i * 4 + 0] = f.x; vv[i * 4 + 1] = f.y; vv[i * 4 + 2] = f.z; vv[i * 4 + 3] = f.w;
        }
        float s1x = sh1_s[0][e], s1y = sh1_s[1][e], s1z = sh1_s[2][e];
#pragma unroll
        for (int u = 0; u < 4; u++) {
            float xa = vv[u * 3 + 0], xb = vv[u * 3 + 1], xc = vv[u * 3 + 2];
            int uu = q * 4 + u;
            vT[0][uu][e] = xa; vT[1][uu][e] = xb; vT[2][uu][e] = xc;
            pT[uu][e] = INV_SQRT3_CONST * (xa * s1x + xb * s1y + xc * s1z);
        }
        const uint4* hsrc = (const uint4*)(hgl + (size_t)(e0 + e) * 128) + q * 4;
        uint4* hdst = (uint4*)(&ovl.h[e][q * 32]);
#pragma unroll
        for (int i = 0; i < 4; i++) hdst[i] = hsrc[i];
    }
    __syncthreads();

    int lane = tid & 63, wave = tid >> 6;
    int el = lane & 15, q4 = lane >> 4;

    // B-fragments (h) resident for whole block
    bf8 hb[4][4];
#pragma unroll
    for (int n = 0; n < 4; n++)
#pragma unroll
        for (int ks = 0; ks < 4; ks++)
            hb[n][ks] = *(const bf8*)&ovl.h[n * 16 + el][ks * 32 + q4 * 8];
    float sh0n[4];
#pragma unroll
    for (int n = 0; n < 4; n++) sh0n[n] = sh0_s[n * 16 + el];
    __syncthreads();   // everyone done reading ovl.h; overlay becomes accC/redB

    // zero accC + redB (contiguous, 4224 floats)
    for (int i = tid; i < 4224; i += 256) ((float*)&ovl.a)[i] = 0.f;
    __syncthreads();

    f4 acc0[4], accB[4];
#pragma unroll
    for (int n = 0; n < 4; n++) { acc0[n] = (f4){0.f,0.f,0.f,0.f}; accB[n] = (f4){0.f,0.f,0.f,0.f}; }

    const u16* abase = w2s + lane * 8;  // + mt*2048 + ks*512 : fully coalesced 1KB/wave-load

    // compute body: 16 MFMAs + contraction for one m-tile (consumes af/b2f by value)
    auto compute = [&](int mt, const bf8* af, float4 b2f) {
        f4 wf[4];
#pragma unroll
        for (int n = 0; n < 4; n++) wf[n] = (f4){b2f.x, b2f.y, b2f.z, b2f.w};
#pragma unroll
        for (int ks = 0; ks < 4; ks++)
#pragma unroll
            for (int n = 0; n < 4; n++)
                wf[n] = __builtin_amdgcn_mfma_f32_16x16x32_bf16(af[ks], hb[n][ks], wf[n], 0, 0, 0);

        int c0 = mt * 16;
        if (c0 < 4096) {                    // A: scale sh0*s[u], out0 rows wave*16..+16
            int u = c0 >> 6;
#pragma unroll
            for (int n = 0; n < 4; n++) {
                float sv = sh0n[n] * sT[u][n * 16 + el];
                acc0[n] += sv * wf[n];
            }
        } else if (c0 < 5120) {             // B: scale s[u] (cross-wave partial)
            int u = (c0 - 4096) >> 4;
#pragma unroll
            for (int n = 0; n < 4; n++) {
                float sv = sT[u][n * 16 + el];
                accB[n] += sv * wf[n];
            }
        } else if (c0 < 5376) {             // C: scales v[i][u], into LDS (cross-wave partial)
            int u = (c0 - 5120) >> 4;
#pragma unroll
            for (int n = 0; n < 4; n++) {
                int e = n * 16 + el;
#pragma unroll
                for (int i = 0; i < 3; i++) {
                    float sv = vT[i][u][e];
#pragma unroll
                    for (int r = 0; r < 4; r++)
                        unsafeAtomicAdd(&ovl.a.accC[i * 16 + q4 * 4 + r][e], sv * wf[n][r]);
                }
            }
        } else {                            // D: scale p[u], out0 rows wave*16..+16
            int u = (c0 - 5376) >> 6;
#pragma unroll
            for (int n = 0; n < 4; n++) {
                float sv = pT[u][n * 16 + el];
                acc0[n] += sv * wf[n];
            }
        }
    };

    // ping-pong double-buffer, manual 2x unroll, NO buffer-rotation copies
    bf8 afA[4], afB[4]; float4 b2A, b2B;
    {
        const u16* pA = abase + (size_t)wave * 2048;
        const u16* pB = abase + (size_t)(wave + 4) * 2048;
#pragma unroll
        for (int ks = 0; ks < 4; ks++) { afA[ks] = *(const bf8*)(pA + ks * 512); afB[ks] = *(const bf8*)(pB + ks * 512); }
        b2A = *(const float4*)(b2 + wave * 16 + q4 * 4);
        b2B = *(const float4*)(b2 + (wave + 4) * 16 + q4 * 4);
    }
    for (int m = wave; m < 400; m += 8) {
        // consume A-buffer (tile m), then immediately re-issue its loads for tile m+8
        compute(m, afA, b2A);
        {
            int mr = (m + 8 < 400) ? (m + 8) : m;
            const u16* p = abase + (size_t)mr * 2048;
#pragma unroll
            for (int ks = 0; ks < 4; ks++) afA[ks] = *(const bf8*)(p + ks * 512);
            b2A = *(const float4*)(b2 + mr * 16 + q4 * 4);
        }
        // consume B-buffer (tile m+4), re-issue for tile m+12
        compute(m + 4, afB, b2B);
        {
            int mr = (m + 12 < 400) ? (m + 12) : (m + 4);
            const u16* p = abase + (size_t)mr * 2048;
#pragma unroll
            for (int ks = 0; ks < 4; ks++) afB[ks] = *(const bf8*)(p + ks * 512);
            b2B = *(const float4*)(b2 + mr * 16 + q4 * 4);
        }
    }

    // accB partials -> redB (disjoint LDS region; safe concurrent with other waves' accC atomics)
#pragma unroll
    for (int n = 0; n < 4; n++) {
        int e = n * 16 + el;
#pragma unroll
        for (int r = 0; r < 4; r++)
            unsafeAtomicAdd(&ovl.a.redB[q4 * 4 + r][e], accB[n][r]);
    }
    __syncthreads();   // all waves done with M-loop (sT reads) + accC/redB atomics

    // stage out0 into sT (now dead): sT[e][c], wave owns cols [wave*16, wave*16+16)
#pragma unroll
    for (int n = 0; n < 4; n++) {
        int e = n * 16 + el;
#pragma unroll
        for (int r = 0; r < 4; r++)
            sT[e][wave * 16 + q4 * 4 + r] = N0_CONST * acc0[n][r];
    }
    __syncthreads();

    // single fully-coalesced 28KB store of tp[e0..e0+64)[0..112) — nontemporal (don't pollute L2)
    float* tpe = tp + (size_t)e0 * 112;
    for (int idx = tid; idx < 64 * 112; idx += 256) {
        int e = idx / 112;
        int c = idx - e * 112;
        float val;
        if (c < 64) {
            val = sT[e][c];
        } else {
            int cr = c - 64;
            int wp = cr / 3;
            int i = cr - wp * 3;
            val = N0_CONST * (ovl.a.redB[wp][e] * sh1_s[i][e] + ovl.a.accC[i * 16 + wp][e] * sh0_s[e]);
        }
        __builtin_nontemporal_store(val, &tpe[idx]);
    }
}

// Per-node segment mean over CSR edge list + residual. Block = node, thread = col.
__global__ __launch_bounds__(128) void k_red(const float* __restrict__ tp,
                                             const int* __restrict__ ptr,
                                             const int* __restrict__ eids,
                                             const float* __restrict__ node_attr,
                                             float* __restrict__ out) {
    int n = blockIdx.x;
    int c = threadIdx.x;
    if (c >= 112) return;
    int a = ptr[n], b = ptr[n + 1];
    float s = 0.f;
    for (int i = a; i < b; i++) {
        int e = eids[i];
        s += tp[(size_t)e * 112 + c];
    }
    float d = fmaxf((float)(b - a), 1.f);
    out[n * 112 + c] = s / d + node_attr[n * 112 + c];
}

extern "C" void kernel_launch(void* const* d_in, const int* in_sizes, int n_in,
                              void* d_out, int out_size, void* d_ws, size_t ws_size,
                              hipStream_t stream) {
    const float* node_attr  = (const float*)d_in[0];
    const int*   edge_index = (const int*)d_in[1];
    const float* edge_attr  = (const float*)d_in[2];
    const float* edge_sh    = (const float*)d_in[3];
    const float* W1         = (const float*)d_in[6];
    const float* b1         = (const float*)d_in[7];
    const float* W2         = (const float*)d_in[8];
    const float* b2         = (const float*)d_in[9];
    float* out = (float*)d_out;

    char* ws = (char*)d_ws;
    u16*   w2s    = (u16*)ws;                     // 6400*128*2  = 1,638,400
    u16*   w1t    = (u16*)(ws + 1638400);         // 128*128*2   =    32,768
    u16*   hgl    = (u16*)(ws + 1671168);         // 32768*128*2 = 8,388,608
    float* tp     = (float*)(ws + 10059776);      // 32768*112*4 = 14,680,064
    int*   deg    = (int*)(ws + 24739840);        // 4096*4      =    16,384
    int*   ptr    = (int*)(ws + 24756224);        // 4097*4 (pad to 16,400)
    int*   cursor = (int*)(ws + 24772624);        // 4096*4      =    16,384
    int*   eids   = (int*)(ws + 24789024);        // 32768*4     =   131,072  -> total ~24.9 MB

    hipMemsetAsync(deg, 0, 16384, stream);
    k_prep<<<544, 256, 0, stream>>>(W2, W1, edge_index, w2s, w1t, deg);
    k_scan<<<1, 64, 0, stream>>>(deg, ptr, cursor);
    k_h<<<512, 256, 0, stream>>>(edge_attr, w1t, b1, edge_index, cursor, eids, hgl);
    k_main<<<512, 256, 0, stream>>>(w2s, hgl, b2, node_attr, edge_index, edge_sh, tp);
    k_red<<<4096, 128, 0, stream>>>(tp, ptr, eids, node_attr, out);
}

// Round 7
// 242.197 us; speedup vs baseline: 1.8300x; 1.2436x over previous
//
#include <hip/hip_runtime.h>

typedef unsigned short u16;
typedef __bf16 bf8 __attribute__((ext_vector_type(8)));
typedef float f4 __attribute__((ext_vector_type(4)));

#define E_EDGES 32768
#define N_NODES 4096
// col layout of w (WNUM=6400): A[u<64][w<64] @0, B[u<64][w<16] @4096, C[u<16][w<16] @5120, D[u<16][w<64] @5376
// k4-group g covers tiles 4g..4g+3; ranges: A g<64, B 64..79, C 80..83, D 84..99 (all 4-aligned)
#define N0_CONST 0.1118033988749895f       // sqrt(1/80); also equals N1*INV_SQRT3
#define INV_SQRT3_CONST 0.5773502691896258f

__device__ __forceinline__ u16 f2bf(float f) {
    unsigned u = __float_as_uint(f);
    u += 0x7FFFu + ((u >> 16) & 1u);   // RNE
    return (u16)(u >> 16);
}

__device__ __forceinline__ void gld16(const u16* g, u16* l) {
    __builtin_amdgcn_global_load_lds((const __attribute__((address_space(1))) void*)g,
                                     (__attribute__((address_space(3))) void*)l, 16, 0, 0);
}

// Weight prep + src-degree histogram, one launch:
//  blocks 0..399:   w2s fragment-order swizzle (tile = 4KB contiguous)
//  blocks 400..415: w1t[c*128+k] = bf16(W1[k*128+c])
//  blocks 416..543: deg histogram over edge src (deg pre-zeroed by memsetAsync)
__global__ __launch_bounds__(256) void k_prep(const float* __restrict__ W2, const float* __restrict__ W1,
                                              const int* __restrict__ edge_index,
                                              u16* __restrict__ w2s, u16* __restrict__ w1t,
                                              int* __restrict__ deg) {
    int b = blockIdx.x;
    int tid = threadIdx.x;
    if (b < 400) {
        int ks = tid >> 6, l = tid & 63;
        int el = l & 15, q4 = l >> 4;
        int c = b * 16 + el;
        u16 tmp[8];
#pragma unroll
        for (int j = 0; j < 8; j++) {
            int k = ks * 32 + q4 * 8 + j;
            tmp[j] = f2bf(W2[(size_t)k * 6400 + c]);
        }
        *(uint4*)(w2s + b * 2048 + ks * 512 + l * 8) = *(uint4*)tmp;
    } else if (b < 416) {
        int t = (b - 400) * 256 + tid;
#pragma unroll
        for (int i = 0; i < 4; i++) {
            int idx = t * 4 + i;                // idx = c*128 + k
            int c = idx >> 7, k = idx & 127;
            w1t[idx] = f2bf(W1[k * 128 + c]);
        }
    } else {
        int t = (b - 416) * 256 + tid;          // 128 blocks * 256 = 32768 = E
        atomicAdd(&deg[edge_index[t]], 1);
    }
}

// Exclusive scan of deg[4096] -> ptr[0..4096] and cursor copy. 1 block, 64 threads.
__global__ void k_scan(const int* __restrict__ deg, int* __restrict__ ptr, int* __restrict__ cursor) {
    int t = threadIdx.x;           // 0..63
    int base = t * 64;
    int s = 0;
    for (int i = 0; i < 64; i++) s += deg[base + i];
    int x = s;
#pragma unroll
    for (int d = 1; d < 64; d <<= 1) {
        int y = __shfl_up(x, d, 64);
        if (t >= d) x += y;
    }
    int run = x - s;               // exclusive prefix
    for (int i = 0; i < 64; i++) {
        ptr[base + i] = run;
        cursor[base + i] = run;
        run += deg[base + i];
    }
    if (t == 63) ptr[4096] = run;
}

// h = relu(edge_attr @ W1 + b1), stored bf16 [E][128]; also fills CSR edge-id list via cursor
__global__ __launch_bounds__(256) void k_h(const float* __restrict__ ea,
                                           const u16* __restrict__ w1t,
                                           const float* __restrict__ b1,
                                           const int* __restrict__ edge_index,
                                           int* __restrict__ cursor,
                                           int* __restrict__ eids,
                                           u16* __restrict__ h) {
    __shared__ alignas(16) u16 ea_s[64][128];
    int tid = threadIdx.x;
    int e0 = blockIdx.x * 64;
    if (tid < 64) {                // CSR fill for this block's 64 edges
        int ge = e0 + tid;
        int s = edge_index[ge];
        int pos = atomicAdd(&cursor[s], 1);
        eids[pos] = ge;
    }
    {
        int e = tid >> 2, q = tid & 3;
        const float4* src = (const float4*)(ea + (size_t)(e0 + e) * 128 + q * 32);
#pragma unroll
        for (int i = 0; i < 8; i++) {
            float4 f = src[i];
            int c = q * 32 + i * 4;
            ea_s[e][c + 0] = f2bf(f.x); ea_s[e][c + 1] = f2bf(f.y);
            ea_s[e][c + 2] = f2bf(f.z); ea_s[e][c + 3] = f2bf(f.w);
        }
    }
    __syncthreads();
    int lane = tid & 63, wave = tid >> 6;
    int el = lane & 15, q4 = lane >> 4;
    f4 acc[4][2];
#pragma unroll
    for (int m = 0; m < 4; m++)
#pragma unroll
        for (int nt = 0; nt < 2; nt++) acc[m][nt] = (f4){0.f, 0.f, 0.f, 0.f};
#pragma unroll
    for (int ks = 0; ks < 4; ks++) {
        bf8 a[4], b[2];
#pragma unroll
        for (int m = 0; m < 4; m++) a[m] = *(const bf8*)&ea_s[m * 16 + el][ks * 32 + q4 * 8];
#pragma unroll
        for (int nt = 0; nt < 2; nt++) {
            int n = wave * 32 + nt * 16 + el;
            b[nt] = *(const bf8*)(w1t + n * 128 + ks * 32 + q4 * 8);
        }
#pragma unroll
        for (int m = 0; m < 4; m++)
#pragma unroll
            for (int nt = 0; nt < 2; nt++)
                acc[m][nt] = __builtin_amdgcn_mfma_f32_16x16x32_bf16(a[m], b[nt], acc[m][nt], 0, 0, 0);
    }
#pragma unroll
    for (int m = 0; m < 4; m++)
#pragma unroll
        for (int nt = 0; nt < 2; nt++) {
            int n = wave * 32 + nt * 16 + el;
            float bias = b1[n];
#pragma unroll
            for (int r = 0; r < 4; r++) {
                int e = e0 + m * 16 + q4 * 4 + r;
                float v = fmaxf(acc[m][nt][r] + bias, 0.f);
                h[(size_t)e * 128 + n] = f2bf(v);
            }
        }
}

// Fused: w = h@W2+b2 tile-by-tile -> contraction -> tp[E][112].  m97-style K-loop:
// A-tiles staged ONCE per block into LDS (global_load_lds x16B, double-buffered, 2 tiles/period);
// all 4 waves process the same mt, wave owns n-tile (16 edges). All contraction state in registers.
__global__ __launch_bounds__(256, 2) void k_main(const u16* __restrict__ w2s,
                                                 const u16* __restrict__ hgl,
                                                 const float* __restrict__ b2,
                                                 const float* __restrict__ node_attr,
                                                 const int* __restrict__ edge_index,
                                                 const float* __restrict__ edge_sh,
                                                 float* __restrict__ tp) {
    __shared__ union {
        u16 h[64][128];                       // 16384 B (prologue)
        u16 stage[2][2][2048];                // 16384 B (loop: [buf][tile][4KB])
    } ovl;
    __shared__ float sT[64][66];              // s[u][e]; epilogue: out0[e][c] (stride 66)
    __shared__ float vT[3][16][66];           // v[i][u][e]; epilogue: out1 flat [e*48+cr]
    __shared__ float pT[16][66];              // INV_SQRT3*(v.sh1)[u][e]
    __shared__ float sh0_s[64];
    __shared__ float sh1_s[3][64];
    __shared__ int dst_s[64];

    int tid = threadIdx.x;
    int e0 = blockIdx.x * 64;

    // phase 1: edge meta
    if (tid < 64) {
        int ge = e0 + tid;
        dst_s[tid] = edge_index[E_EDGES + ge];
        float4 sh = *(const float4*)(edge_sh + (size_t)ge * 4);
        sh0_s[tid] = sh.x; sh1_s[0][tid] = sh.y; sh1_s[1][tid] = sh.z; sh1_s[2][tid] = sh.w;
    }
    __syncthreads();

    // phase 2: node features (transposed into LDS) + h tile into ovl.h
    {
        int e = tid >> 2, q = tid & 3;
        int dst = dst_s[e];
        const float* xp = node_attr + (size_t)dst * 112;
#pragma unroll
        for (int i = 0; i < 4; i++) {
            float4 f = *(const float4*)(xp + q * 16 + i * 4);
            int u = q * 16 + i * 4;
            sT[u + 0][e] = f.x; sT[u + 1][e] = f.y; sT[u + 2][e] = f.z; sT[u + 3][e] = f.w;
        }
        float vv[12];
#pragma unroll
        for (int i = 0; i < 3; i++) {
            float4 f = *(const float4*)(xp + 64 + q * 12 + i * 4);
            vv[i * 4 + 0] = f.x; vv[i * 4 + 1] = f.y; vv[i * 4 + 2] = f.z; vv[i * 4 + 3] = f.w;
        }
        float s1x = sh1_s[0][e], s1y = sh1_s[1][e], s1z = sh1_s[2][e];
#pragma unroll
        for (int u = 0; u < 4; u++) {
            float xa = vv[u * 3 + 0], xb = vv[u * 3 + 1], xc = vv[u * 3 + 2];
            int uu = q * 4 + u;
            vT[0][uu][e] = xa; vT[1][uu][e] = xb; vT[2][uu][e] = xc;
            pT[uu][e] = INV_SQRT3_CONST * (xa * s1x + xb * s1y + xc * s1z);
        }
        const uint4* hsrc = (const uint4*)(hgl + (size_t)(e0 + e) * 128) + q * 4;
        uint4* hdst = (uint4*)(&ovl.h[e][q * 32]);
#pragma unroll
        for (int i = 0; i < 4; i++) hdst[i] = hsrc[i];
    }
    __syncthreads();

    int lane = tid & 63, wave = tid >> 6;
    int el = lane & 15, q4 = lane >> 4;
    int eln = wave * 16 + el;                 // this wave's edge for this lane

    // B-fragments: wave owns n-tile = its 16 edges -> only 4 bf8 (16 VGPRs)
    bf8 hb[4];
#pragma unroll
    for (int ks = 0; ks < 4; ks++)
        hb[ks] = *(const bf8*)&ovl.h[eln][ks * 32 + q4 * 8];
    float sh0n = sh0_s[eln];
    __syncthreads();   // h region free -> becomes stage buffers

    f4 acc0[4], accB, accC[3];
#pragma unroll
    for (int j = 0; j < 4; j++) acc0[j] = (f4){0.f, 0.f, 0.f, 0.f};
    accB = (f4){0.f, 0.f, 0.f, 0.f};
#pragma unroll
    for (int i = 0; i < 3; i++) accC[i] = (f4){0.f, 0.f, 0.f, 0.f};

    auto mfma4 = [&](const u16* st, float4 bb) -> f4 {
        const u16* sp = st + lane * 8;
        bf8 a0 = *(const bf8*)(sp + 0);
        bf8 a1 = *(const bf8*)(sp + 512);
        bf8 a2 = *(const bf8*)(sp + 1024);
        bf8 a3 = *(const bf8*)(sp + 1536);
        f4 w = (f4){bb.x, bb.y, bb.z, bb.w};
        w = __builtin_amdgcn_mfma_f32_16x16x32_bf16(a0, hb[0], w, 0, 0, 0);
        w = __builtin_amdgcn_mfma_f32_16x16x32_bf16(a1, hb[1], w, 0, 0, 0);
        w = __builtin_amdgcn_mfma_f32_16x16x32_bf16(a2, hb[2], w, 0, 0, 0);
        w = __builtin_amdgcn_mfma_f32_16x16x32_bf16(a3, hb[3], w, 0, 0, 0);
        return w;
    };

    // preload tiles 0,1 -> buf 0
    {
        const u16* g = w2s + tid * 8;
        gld16(g, &ovl.stage[0][0][tid * 8]);
        gld16(g + 2048, &ovl.stage[0][1][tid * 8]);
    }

    for (int k4 = 0; k4 < 100; k4++) {
        f4 wf[4];
        // period A: consume buf0 (tiles 4k4, 4k4+1); prefetch tiles 4k4+2,3 -> buf1
        __syncthreads();
        {
            const u16* g = w2s + (size_t)(4 * k4 + 2) * 2048 + tid * 8;
            gld16(g, &ovl.stage[1][0][tid * 8]);
            gld16(g + 2048, &ovl.stage[1][1][tid * 8]);
        }
        float4 b2f0 = *(const float4*)(b2 + (4 * k4 + 0) * 16 + q4 * 4);
        float4 b2f1 = *(const float4*)(b2 + (4 * k4 + 1) * 16 + q4 * 4);
        wf[0] = mfma4(&ovl.stage[0][0][0], b2f0);
        wf[1] = mfma4(&ovl.stage[0][1][0], b2f1);
        // period B: consume buf1 (tiles 4k4+2,3); prefetch tiles 4k4+4,5 -> buf0
        __syncthreads();
        if (k4 < 99) {
            const u16* g = w2s + (size_t)(4 * k4 + 4) * 2048 + tid * 8;
            gld16(g, &ovl.stage[0][0][tid * 8]);
            gld16(g + 2048, &ovl.stage[0][1][tid * 8]);
        }
        float4 b2f2 = *(const float4*)(b2 + (4 * k4 + 2) * 16 + q4 * 4);
        float4 b2f3 = *(const float4*)(b2 + (4 * k4 + 3) * 16 + q4 * 4);
        wf[2] = mfma4(&ovl.stage[1][0][0], b2f2);
        wf[3] = mfma4(&ovl.stage[1][1][0], b2f3);

        // contraction for the 4-tile group (uniform branch; all acc indices static)
        if (k4 < 64) {                        // A: u = k4, out0 col-blocks j*16
            float sv = sh0n * sT[k4][eln];
#pragma unroll
            for (int j = 0; j < 4; j++) acc0[j] += sv * wf[j];
        } else if (k4 < 80) {                 // B: u = 4*(k4-64)+j
            int u0 = (k4 - 64) * 4;
#pragma unroll
            for (int j = 0; j < 4; j++) accB += sT[u0 + j][eln] * wf[j];
        } else if (k4 < 84) {                 // C: u = 4*(k4-80)+j
            int u0 = (k4 - 80) * 4;
#pragma unroll
            for (int j = 0; j < 4; j++)
#pragma unroll
                for (int i = 0; i < 3; i++) accC[i] += vT[i][u0 + j][eln] * wf[j];
        } else {                              // D: u = k4-84
            float pv = pT[k4 - 84][eln];
#pragma unroll
            for (int j = 0; j < 4; j++) acc0[j] += pv * wf[j];
        }
    }

    __syncthreads();   // all waves done reading sT/vT/pT -> reuse for output staging

    // out0 -> sT[e][c] (c = j*16 + q4*4 + r)
#pragma unroll
    for (int j = 0; j < 4; j++)
#pragma unroll
        for (int r = 0; r < 4; r++)
            sT[eln][j * 16 + q4 * 4 + r] = N0_CONST * acc0[j][r];
    // out1 -> vT flat [e*48 + wp*3 + i], wp = q4*4+r
    {
        float* vflat = (float*)vT;
        float s0v = sh0_s[eln];
        float s1v0 = sh1_s[0][eln], s1v1 = sh1_s[1][eln], s1v2 = sh1_s[2][eln];
#pragma unroll
        for (int r = 0; r < 4; r++) {
            int wp = q4 * 4 + r;
            vflat[eln * 48 + wp * 3 + 0] = N0_CONST * (accB[r] * s1v0 + accC[0][r] * s0v);
            vflat[eln * 48 + wp * 3 + 1] = N0_CONST * (accB[r] * s1v1 + accC[1][r] * s0v);
            vflat[eln * 48 + wp * 3 + 2] = N0_CONST * (accB[r] * s1v2 + accC[2][r] * s0v);
        }
    }
    __syncthreads();

    // single coalesced 28KB store of tp[e0..e0+64)[0..112) — nontemporal
    {
        const float* vflat = (const float*)vT;
        float* tpe = tp + (size_t)e0 * 112;
        for (int idx = tid; idx < 64 * 112; idx += 256) {
            int e = idx / 112;
            int c = idx - e * 112;
            float val = (c < 64) ? sT[e][c] : vflat[e * 48 + (c - 64)];
            __builtin_nontemporal_store(val, &tpe[idx]);
        }
    }
}

// Per-node segment mean over CSR edge list + residual. Block = node, thread = col.
__global__ __launch_bounds__(128) void k_red(const float* __restrict__ tp,
                                             const int* __restrict__ ptr,
                                             const int* __restrict__ eids,
                                             const float* __restrict__ node_attr,
                                             float* __restrict__ out) {
    int n = blockIdx.x;
    int c = threadIdx.x;
    if (c >= 112) return;
    int a = ptr[n], b = ptr[n + 1];
    float s = 0.f;
    for (int i = a; i < b; i++) {
        int e = eids[i];
        s += tp[(size_t)e * 112 + c];
    }
    float d = fmaxf((float)(b - a), 1.f);
    out[n * 112 + c] = s / d + node_attr[n * 112 + c];
}

extern "C" void kernel_launch(void* const* d_in, const int* in_sizes, int n_in,
                              void* d_out, int out_size, void* d_ws, size_t ws_size,
                              hipStream_t stream) {
    const float* node_attr  = (const float*)d_in[0];
    const int*   edge_index = (const int*)d_in[1];
    const float* edge_attr  = (const float*)d_in[2];
    const float* edge_sh    = (const float*)d_in[3];
    const float* W1         = (const float*)d_in[6];
    const float* b1         = (const float*)d_in[7];
    const float* W2         = (const float*)d_in[8];
    const float* b2         = (const float*)d_in[9];
    float* out = (float*)d_out;

    char* ws = (char*)d_ws;
    u16*   w2s    = (u16*)ws;                     // 6400*128*2  = 1,638,400
    u16*   w1t    = (u16*)(ws + 1638400);         // 128*128*2   =    32,768
    u16*   hgl    = (u16*)(ws + 1671168);         // 32768*128*2 = 8,388,608
    float* tp     = (float*)(ws + 10059776);      // 32768*112*4 = 14,680,064
    int*   deg    = (int*)(ws + 24739840);        // 4096*4
    int*   ptr    = (int*)(ws + 24756224);        // 4097*4
    int*   cursor = (int*)(ws + 24772624);        // 4096*4
    int*   eids   = (int*)(ws + 24789024);        // 32768*4

    hipMemsetAsync(deg, 0, 16384, stream);
    k_prep<<<544, 256, 0, stream>>>(W2, W1, edge_index, w2s, w1t, deg);
    k_scan<<<1, 64, 0, stream>>>(deg, ptr, cursor);
    k_h<<<512, 256, 0, stream>>>(edge_attr, w1t, b1, edge_index, cursor, eids, hgl);
    k_main<<<512, 256, 0, stream>>>(w2s, hgl, b2, node_attr, edge_index, edge_sh, tp);
    k_red<<<4096, 128, 0, stream>>>(tp, ptr, eids, node_attr, out);
}